// Round 8
// baseline (119.210 us; speedup 1.0000x reference)
//
#include <hip/hip_runtime.h>
#include <math.h>

constexpr int NN = 2048;
constexpr int DD = 128;
constexpr float EPSF = 1e-7f;
constexpr float MAXN = 1.0f - 1e-5f;

extern "C" __global__ __launch_bounds__(256, 2)
void mmp_kernel(const float* __restrict__ x,
                const float* __restrict__ adj,
                const float* __restrict__ W,
                const float* __restrict__ bias,
                float* __restrict__ out)
{
    __shared__ float sW[DD * DD];     // 64 KB: weight staged
    __shared__ float s_mt[4][DD];     // per-wave mean_t

    const int tid  = threadIdx.x;
    const int lane = tid & 63;
    const int wv   = tid >> 6;
    const int row  = (int)blockIdx.x * 4 + wv;

    // ---- stage W (128x128 fp32) into LDS, 16 float4 per thread ----
    {
        const float4* Wv4 = reinterpret_cast<const float4*>(W);
        float4* sWv4 = reinterpret_cast<float4*>(sW);
#pragma unroll
        for (int k = 0; k < 16; ++k)
            sWv4[k * 256 + tid] = Wv4[k * 256 + tid];
    }

    // ---- load x_i (lane holds elems lane and lane+64) ----
    const float xi0 = x[row * DD + lane];
    const float xi1 = x[row * DD + 64 + lane];

    float x2 = xi0 * xi0 + xi1 * xi1;
#pragma unroll
    for (int off = 32; off; off >>= 1) x2 += __shfl_xor(x2, off);

    const float s = fmaxf(1.0f - x2, EPSF);   // = 2/lambda_x

    float acc0 = 0.0f, acc1 = 0.0f;   // sum_j coef_j * x_j  (distributed)
    float alpha = 0.0f;               // sum_j adj*g*a  (uniform across lanes)
    float dacc  = 0.0f;               // degree accumulator (per-lane partial)

    const float* arow = adj + (size_t)row * NN;
#pragma unroll 1
    for (int chunk = 0; chunk < NN / 256; ++chunk) {
        float4 av = reinterpret_cast<const float4*>(arow)[chunk * 64 + lane];
        dacc += (av.x + av.y) + (av.z + av.w);
#pragma unroll
        for (int v = 0; v < 4; ++v) {
            float val = (v == 0) ? av.x : (v == 1) ? av.y : (v == 2) ? av.z : av.w;
            unsigned long long m = __ballot(val != 0.0f);
            while (m) {
                int b = __ffsll(m) - 1;
                m &= m - 1;
                const int j = chunk * 256 + b * 4 + v;
                const float w = __shfl(val, b);

                const float xj0 = x[j * DD + lane];
                const float xj1 = x[j * DD + 64 + lane];

                float c  = xi0 * xj0 + xi1 * xj1;
                float y2 = xj0 * xj0 + xj1 * xj1;
#pragma unroll
                for (int off = 32; off; off >>= 1) {
                    c  += __shfl_xor(c, off);
                    y2 += __shfl_xor(y2, off);
                }

                const float t   = 1.0f - 2.0f * c + y2;
                const float den = fmaxf(1.0f - 2.0f * c + x2 * y2, 1e-15f);
                const float inv = 1.0f / den;
                const float a   = -t * inv;
                const float bb  = (1.0f - x2) * inv;
                const float mn2 = fmaxf(a * a * x2 + 2.0f * a * bb * c + bb * bb * y2, 0.0f);
                const float mn  = sqrtf(mn2);
                const float g   = atanhf(fminf(mn, MAXN)) / fmaxf(mn, EPSF);
                const float wg  = w * g;
                const float cf  = wg * bb;
                alpha += wg * a;
                acc0  = fmaf(cf, xj0, acc0);
                acc1  = fmaf(cf, xj1, acc1);
            }
        }
    }

#pragma unroll
    for (int off = 32; off; off >>= 1) dacc += __shfl_xor(dacc, off);
    const float deg = fmaxf(dacc, 1e-8f);

    // mean_t = (s/deg) * (alpha * x_i + acc)
    const float fsc = s / deg;
    s_mt[wv][lane]      = fsc * fmaf(alpha, xi0, acc0);
    s_mt[wv][64 + lane] = fsc * fmaf(alpha, xi1, acc1);

    __syncthreads();   // covers sW staging + own s_mt visibility

    // ---- transformed = mean_t @ W + bias ----
    float v0 = bias[lane];
    float v1 = bias[64 + lane];
#pragma unroll 8
    for (int k = 0; k < DD; ++k) {
        const float mk = s_mt[wv][k];
        v0 = fmaf(mk, sW[k * DD + lane], v0);
        v1 = fmaf(mk, sW[k * DD + 64 + lane], v1);
    }

    // ---- expmap_{x_i}(v) ----
    float vn2 = v0 * v0 + v1 * v1;
    float xv  = xi0 * v0 + xi1 * v1;
#pragma unroll
    for (int off = 32; off; off >>= 1) {
        vn2 += __shfl_xor(vn2, off);
        xv  += __shfl_xor(xv, off);
    }
    const float vn  = sqrtf(vn2);
    const float th  = tanhf(vn / s);          // tanh(0.5*lambda*||v||)
    const float fac = th / fmaxf(vn, EPSF);
    const float sec0 = fac * v0, sec1 = fac * v1;
    const float y2s = fac * fac * vn2;        // ||second||^2
    const float xy  = fac * xv;               // <x_i, second>
    const float nc  = 1.0f + 2.0f * xy + y2s;
    const float dn  = fmaxf(1.0f + 2.0f * xy + x2 * y2s, 1e-15f);
    const float idn = 1.0f / dn;
    const float sx  = 1.0f - x2;

    out[row * DD + lane]      = (nc * xi0 + sx * sec0) * idn;
    out[row * DD + 64 + lane] = (nc * xi1 + sx * sec1) * idn;
}

extern "C" void kernel_launch(void* const* d_in, const int* in_sizes, int n_in,
                              void* d_out, int out_size, void* d_ws, size_t ws_size,
                              hipStream_t stream) {
    const float* x    = (const float*)d_in[0];
    const float* adj  = (const float*)d_in[1];
    const float* W    = (const float*)d_in[2];
    const float* bias = (const float*)d_in[3];
    float* out        = (float*)d_out;

    dim3 grid(NN / 4);   // one wave per row, 4 rows per block
    dim3 block(256);
    mmp_kernel<<<grid, block, 0, stream>>>(x, adj, W, bias, out);
}

// Round 9
// 84.467 us; speedup vs baseline: 1.4113x; 1.4113x over previous
//
#include <hip/hip_runtime.h>
#include <math.h>

constexpr int NN = 2048;
constexpr int DD = 128;
constexpr float EPSF = 1e-7f;
constexpr float MAXN = 1.0f - 1e-5f;

// Wave-internal LDS RAW fence (cross-lane data through LDS within one wave).
#define LDS_FENCE() asm volatile("s_waitcnt lgkmcnt(0)" ::: "memory")

extern "C" __global__ __launch_bounds__(256, 2)
void mmp_kernel(const float* __restrict__ x,
                const float* __restrict__ adj,
                const float* __restrict__ W,
                const float* __restrict__ bias,
                float* __restrict__ out)
{
    // Per-wave scratch only; no block-wide sync anywhere.
    __shared__ int   sj [4][128];   // compacted column indices (batch buffer)
    __shared__ float swt[4][128];   // compacted adj weights
    __shared__ float scf[4][64];    // per-pair coefficient for axpy broadcast
    __shared__ float sxi[4][DD];    // x_i staged for broadcast in dot loop
    __shared__ float smt[4][DD];    // mean_t staged for matvec broadcast

    const int tid  = threadIdx.x;
    const int lane = tid & 63;
    const int wv   = tid >> 6;
    const int row  = (int)blockIdx.x * 4 + wv;

    // ---- x_i: lane holds elems lane and lane+64; also staged to LDS ----
    const float xi0 = x[row * DD + lane];
    const float xi1 = x[row * DD + 64 + lane];
    sxi[wv][lane]      = xi0;
    sxi[wv][64 + lane] = xi1;

    float x2 = xi0 * xi0 + xi1 * xi1;
#pragma unroll
    for (int off = 32; off; off >>= 1) x2 += __shfl_xor(x2, off);
    const float s = fmaxf(1.0f - x2, EPSF);    // = 2/lambda_x
    const float one_m_x2 = 1.0f - x2;
    LDS_FENCE();                               // sxi visible wave-wide

    float acc0 = 0.0f, acc1 = 0.0f;  // sum_j coef_j * x_j (distributed over lanes)
    float alpha = 0.0f;              // sum_j adj*g*a (uniform)
    float dacc  = 0.0f;              // degree partial

    const float4* arow4 = reinterpret_cast<const float4*>(adj + (size_t)row * NN);
    int cnt = 0;                     // slots currently in buffer (wave-uniform)

    // Process one batch of cn (<=64) compacted pairs: lane-parallel scalar math.
    auto process_batch = [&](int cn) {
        const int   jj = (lane < cn) ? sj [wv][lane] : row;   // row => exact zero contrib
        const float ww = (lane < cn) ? swt[wv][lane] : 0.0f;

        // c = <x_i, x_j>, y2 = <x_j, x_j> : per-lane serial fp32 chain, no shuffles
        const float4* xj4 = reinterpret_cast<const float4*>(x + (size_t)jj * DD);
        const float4* xi4 = reinterpret_cast<const float4*>(sxi[wv]);
        float c = 0.0f, y2 = 0.0f;
#pragma unroll 8
        for (int k = 0; k < DD / 4; ++k) {
            const float4 a = xi4[k];    // LDS broadcast (same addr all lanes)
            const float4 b = xj4[k];    // per-lane gather, L1/L2-resident
            c  = fmaf(a.x, b.x, fmaf(a.y, b.y, fmaf(a.z, b.z, fmaf(a.w, b.w, c))));
            y2 = fmaf(b.x, b.x, fmaf(b.y, b.y, fmaf(b.z, b.z, fmaf(b.w, b.w, y2))));
        }

        // scalar logmap-collapse chain — fully lane-parallel (64 pairs at once)
        const float t   = 1.0f - 2.0f * c + y2;
        const float den = fmaxf(1.0f - 2.0f * c + x2 * y2, 1e-15f);
        const float inv = 1.0f / den;
        const float a_  = -t * inv;
        const float b_  = one_m_x2 * inv;
        const float mn2 = fmaxf(a_ * a_ * x2 + 2.0f * a_ * b_ * c + b_ * b_ * y2, 0.0f);
        const float mn  = sqrtf(mn2);
        const float g   = atanhf(fminf(mn, MAXN)) / fmaxf(mn, EPSF);
        const float wg  = ww * g;
        scf[wv][lane] = wg * b_;          // coefficient for the axpy pass

        float wga = wg * a_;              // one butterfly per BATCH (not per pair)
#pragma unroll
        for (int off = 32; off; off >>= 1) wga += __shfl_xor(wga, off);
        alpha += wga;
        LDS_FENCE();                      // scf visible wave-wide

        // axpy: acc += cf_p * x_{j_p}; independent coalesced loads -> pipelined
        for (int p = 0; p < cn; ++p) {
            const float cfp = scf[wv][p];
            const int   jp  = sj [wv][p];
            acc0 = fmaf(cfp, x[jp * DD + lane],      acc0);
            acc1 = fmaf(cfp, x[jp * DD + 64 + lane], acc1);
        }
    };

    // ---- scan adj row, ballot-compact nonzeros into slots ----
#pragma unroll 1
    for (int chunk = 0; chunk < NN / 256; ++chunk) {
        const float4 av = arow4[chunk * 64 + lane];
        dacc += (av.x + av.y) + (av.z + av.w);
#pragma unroll
        for (int v = 0; v < 4; ++v) {
            const float val = (v == 0) ? av.x : (v == 1) ? av.y : (v == 2) ? av.z : av.w;
            const bool pnz = (val != 0.0f);
            const unsigned long long m = __ballot(pnz);
            if (pnz) {
                const int rank = __popcll(m & ((1ull << lane) - 1ull));
                sj [wv][cnt + rank] = chunk * 256 + lane * 4 + v;
                swt[wv][cnt + rank] = val;
            }
            cnt += __popcll(m);
            if (cnt >= 64) {              // rare flush (E[nnz]=33); correctness path
                LDS_FENCE();
                process_batch(64);
                const int rem = cnt - 64;
                if (lane < rem) {
                    sj [wv][lane] = sj [wv][64 + lane];
                    swt[wv][lane] = swt[wv][64 + lane];
                }
                LDS_FENCE();
                cnt = rem;
            }
        }
    }
    if (cnt > 0) { LDS_FENCE(); process_batch(cnt); }

    // ---- degree, mean_t ----
#pragma unroll
    for (int off = 32; off; off >>= 1) dacc += __shfl_xor(dacc, off);
    const float deg = fmaxf(dacc, 1e-8f);
    const float fsc = s / deg;
    smt[wv][lane]      = fsc * fmaf(alpha, xi0, acc0);
    smt[wv][64 + lane] = fsc * fmaf(alpha, xi1, acc1);
    LDS_FENCE();

    // ---- transformed = mean_t @ W + bias  (W from global: L1/L2 broadcast) ----
    float v0 = bias[lane];
    float v1 = bias[64 + lane];
#pragma unroll 8
    for (int k = 0; k < DD; ++k) {
        const float mk = smt[wv][k];
        v0 = fmaf(mk, W[k * DD + lane],      v0);
        v1 = fmaf(mk, W[k * DD + 64 + lane], v1);
    }

    // ---- expmap_{x_i}(v) ----
    float vn2 = v0 * v0 + v1 * v1;
    float xv  = xi0 * v0 + xi1 * v1;
#pragma unroll
    for (int off = 32; off; off >>= 1) {
        vn2 += __shfl_xor(vn2, off);
        xv  += __shfl_xor(xv, off);
    }
    const float vn  = sqrtf(vn2);
    const float th  = tanhf(vn / s);           // tanh(0.5*lambda*||v||)
    const float fac = th / fmaxf(vn, EPSF);
    const float sec0 = fac * v0, sec1 = fac * v1;
    const float y2s = fac * fac * vn2;         // ||second||^2
    const float xy  = fac * xv;                // <x_i, second>
    const float nc  = 1.0f + 2.0f * xy + y2s;
    const float dn  = fmaxf(1.0f + 2.0f * xy + x2 * y2s, 1e-15f);
    const float idn = 1.0f / dn;

    out[row * DD + lane]      = (nc * xi0 + one_m_x2 * sec0) * idn;
    out[row * DD + 64 + lane] = (nc * xi1 + one_m_x2 * sec1) * idn;
}

extern "C" void kernel_launch(void* const* d_in, const int* in_sizes, int n_in,
                              void* d_out, int out_size, void* d_ws, size_t ws_size,
                              hipStream_t stream) {
    const float* x    = (const float*)d_in[0];
    const float* adj  = (const float*)d_in[1];
    const float* W    = (const float*)d_in[2];
    const float* bias = (const float*)d_in[3];
    float* out        = (float*)d_out;

    dim3 grid(NN / 4);   // one wave per row, 4 rows per block
    dim3 block(256);
    mmp_kernel<<<grid, block, 0, stream>>>(x, adj, W, bias, out);
}